// Round 8
// baseline (2020.100 us; speedup 1.0000x reference)
//
#include <hip/hip_runtime.h>
#include <hip/hip_bf16.h>

#define BB 4
#define SS 2048
#define FF 512
#define HH 8
#define EPSV 1e-5f

typedef __attribute__((ext_vector_type(8))) short bf16x8;
typedef __attribute__((ext_vector_type(4))) float f32x4;

#define MFMA_B16(a,b,c) __builtin_amdgcn_mfma_f32_16x16x32_bf16((a),(b),(c),0,0,0)

__device__ __forceinline__ short f2bf(float v) {
    union { __hip_bfloat16 b; short s; } u; u.b = __float2bfloat16(v); return u.s;
}
__device__ __forceinline__ float bf2f(short s) {
    union { short s; __hip_bfloat16 b; } u; u.s = s; return __bfloat162float(u.b);
}
__device__ __forceinline__ unsigned pack2(short a, short b) {
    return (unsigned)(unsigned short)a | ((unsigned)(unsigned short)b << 16);
}

// ============ prep: split x into hi/lo bf16 planes ============
__global__ __launch_bounds__(256)
void prep_x_kernel(const float* __restrict__ x, short* __restrict__ xhi, short* __restrict__ xlo)
{
    const int n4 = BB*SS*FF/4;
    for (int i = blockIdx.x*256 + threadIdx.x; i < n4; i += gridDim.x*256) {
        float4 v = *(const float4*)&x[(size_t)i*4];
        short h0=f2bf(v.x),h1=f2bf(v.y),h2=f2bf(v.z),h3=f2bf(v.w);
        uint2 ph, pl;
        ph.x = pack2(h0,h1); ph.y = pack2(h2,h3);
        pl.x = pack2(f2bf(v.x-bf2f(h0)), f2bf(v.y-bf2f(h1)));
        pl.y = pack2(f2bf(v.z-bf2f(h2)), f2bf(v.w-bf2f(h3)));
        *(uint2*)&xhi[(size_t)i*4] = ph;
        *(uint2*)&xlo[(size_t)i*4] = pl;
    }
}

// ============ prep: transpose fp32 [R][C] -> hi/lo bf16 [C][R], per mat z ============
__global__ __launch_bounds__(256)
void prep_t_kernel(const float* __restrict__ in, short* __restrict__ oh, short* __restrict__ ol,
                   int R, int C)
{
    __shared__ float Ts[64][68];
    const int t = threadIdx.x;
    const int c0 = blockIdx.x*64, r0 = blockIdx.y*64;
    const size_t mo = (size_t)blockIdx.z * R * C;
    #pragma unroll
    for (int i = 0; i < 4; ++i) {
        int idx = t + 256*i;
        int rr = idx >> 4, c4 = (idx & 15)*4;
        float4 v = *(const float4*)&in[mo + (size_t)(r0+rr)*C + c0 + c4];
        Ts[rr][c4] = v.x; Ts[rr][c4+1] = v.y; Ts[rr][c4+2] = v.z; Ts[rr][c4+3] = v.w;
    }
    __syncthreads();
    #pragma unroll
    for (int i = 0; i < 4; ++i) {
        int idx = t + 256*i;
        int cc = idx >> 4, k4 = (idx & 15)*4;
        short h[4], l[4];
        #pragma unroll
        for (int j = 0; j < 4; ++j) {
            float v = Ts[k4+j][cc];
            h[j] = f2bf(v); l[j] = f2bf(v - bf2f(h[j]));
        }
        uint2 ph, pl;
        ph.x = pack2(h[0],h[1]); ph.y = pack2(h[2],h[3]);
        pl.x = pack2(l[0],l[1]); pl.y = pack2(l[2],l[3]);
        *(uint2*)&oh[mo + (size_t)(c0+cc)*R + r0 + k4] = ph;
        *(uint2*)&ol[mo + (size_t)(c0+cc)*R + r0 + k4] = pl;
    }
}

// ============ Kernel 1: QKV projection, split-bf16 MFMA ============
// grid (FF/128=4, SS/128=16, 3*nbh), block 256 (4 waves, 2x2 of 64x64)
__global__ __launch_bounds__(256,2)
void proj_kernel(const short* __restrict__ xhi, const short* __restrict__ xlo,
                 const short* __restrict__ Wth, const short* __restrict__ Wtl,
                 short* __restrict__ Qhi, short* __restrict__ Qlo,
                 short* __restrict__ Khi, short* __restrict__ Klo,
                 short* __restrict__ Vt, int b_base, int nbh)
{
    __shared__ short Ah[128][40], Al[128][40];   // [m][k]
    __shared__ short Bh[128][40], Bl[128][40];   // [n][k] (W^T)
    const int t = threadIdx.x, lane = t & 63, w = t >> 6;
    const int l15 = lane & 15, l16 = lane >> 4;
    const int wm = (w >> 1)*64, wn = (w & 1)*64;
    const int n0 = blockIdx.x*128, m0 = blockIdx.y*128;
    const int which = blockIdx.z / nbh;
    const int bh = blockIdx.z % nbh;
    const int h = bh % HH;
    const short* xh = xhi + (size_t)(b_base + bh/HH)*SS*FF;
    const short* xl = xlo + (size_t)(b_base + bh/HH)*SS*FF;
    const short* Bgh = Wth + (size_t)(which*HH + h)*FF*FF;
    const short* Bgl = Wtl + (size_t)(which*HH + h)*FF*FF;

    f32x4 acc[4][4] = {};

    for (int k0 = 0; k0 < FF; k0 += 32) {
        __syncthreads();
        #pragma unroll
        for (int i = 0; i < 2; ++i) {
            int idx = t + 256*i;
            int row = idx >> 2, c8 = (idx & 3)*8;
            *(bf16x8*)&Ah[row][c8] = *(const bf16x8*)&xh[(size_t)(m0+row)*FF + k0 + c8];
            *(bf16x8*)&Al[row][c8] = *(const bf16x8*)&xl[(size_t)(m0+row)*FF + k0 + c8];
            *(bf16x8*)&Bh[row][c8] = *(const bf16x8*)&Bgh[(size_t)(n0+row)*FF + k0 + c8];
            *(bf16x8*)&Bl[row][c8] = *(const bf16x8*)&Bgl[(size_t)(n0+row)*FF + k0 + c8];
        }
        __syncthreads();
        bf16x8 a_h[4], a_l[4], b_h[4], b_l[4];
        #pragma unroll
        for (int mf = 0; mf < 4; ++mf) {
            a_h[mf] = *(const bf16x8*)&Ah[wm + mf*16 + l15][l16*8];
            a_l[mf] = *(const bf16x8*)&Al[wm + mf*16 + l15][l16*8];
        }
        #pragma unroll
        for (int nf = 0; nf < 4; ++nf) {
            b_h[nf] = *(const bf16x8*)&Bh[wn + nf*16 + l15][l16*8];
            b_l[nf] = *(const bf16x8*)&Bl[wn + nf*16 + l15][l16*8];
        }
        #pragma unroll
        for (int mf = 0; mf < 4; ++mf)
        #pragma unroll
        for (int nf = 0; nf < 4; ++nf) {
            acc[mf][nf] = MFMA_B16(a_h[mf], b_h[nf], acc[mf][nf]);
            acc[mf][nf] = MFMA_B16(a_h[mf], b_l[nf], acc[mf][nf]);
            acc[mf][nf] = MFMA_B16(a_l[mf], b_h[nf], acc[mf][nf]);
        }
    }
    if (which < 2) {
        short* Ph = ((which==0) ? Qhi : Khi) + (size_t)bh*SS*FF;
        short* Pl = ((which==0) ? Qlo : Klo) + (size_t)bh*SS*FF;
        #pragma unroll
        for (int mf = 0; mf < 4; ++mf)
        #pragma unroll
        for (int nf = 0; nf < 4; ++nf)
        #pragma unroll
        for (int r = 0; r < 4; ++r) {
            int rw = m0 + wm + mf*16 + l16*4 + r;
            int cl = n0 + wn + nf*16 + l15;
            float v = acc[mf][nf][r];
            short hh = f2bf(v);
            Ph[(size_t)rw*FF + cl] = hh;
            Pl[(size_t)rw*FF + cl] = f2bf(v - bf2f(hh));
        }
    } else {
        short* Vp = Vt + (size_t)bh*FF*SS;   // [f][s]
        #pragma unroll
        for (int mf = 0; mf < 4; ++mf)
        #pragma unroll
        for (int nf = 0; nf < 4; ++nf) {
            int cl = n0 + wn + nf*16 + l15;       // feature
            int rw = m0 + wm + mf*16 + l16*4;     // s base (4 consecutive)
            uint2 pk;
            pk.x = pack2(f2bf(acc[mf][nf][0]), f2bf(acc[mf][nf][1]));
            pk.y = pack2(f2bf(acc[mf][nf][2]), f2bf(acc[mf][nf][3]));
            *(uint2*)&Vp[(size_t)cl*SS + rw] = pk;
        }
    }
}

// ============ Kernel 2: flash attention, split-bf16 QK + bf16 PV ============
// grid (SS/64=32, nbh), block 512 (8 waves = 2 waves/SIMD).
// wave w: q-row group g=w>>1 (rows 16g..16g+15), half h=w&1
//   QK: keys [16h,16h+16);  PV: features [256h,256h+256)
__global__ __launch_bounds__(512,2)
void attn_kernel(const float* __restrict__ x,
                 const short* __restrict__ Qhi, const short* __restrict__ Qlo,
                 const short* __restrict__ Khi, const short* __restrict__ Klo,
                 const short* __restrict__ VtG,
                 short* __restrict__ Zhi, short* __restrict__ Zlo, int b_base)
{
    __shared__ short Ksh[32][520], Ksl[32][520];  // K tile hi/lo [key][f]
    __shared__ short Vts[512][40];                // V^T tile [f][kv]
    __shared__ float Ps[64][33];                  // scores
    __shared__ short Pb[64][40];                  // probs bf16
    __shared__ float mrow[64], lrow[64], srow[64];

    const int t = threadIdx.x, lane = t & 63, w = t >> 6;
    const int l15 = lane & 15, l16 = lane >> 4;
    const int g = w >> 1, h = w & 1;
    const int s0 = blockIdx.x * 64;
    const int bh = blockIdx.y;

    const size_t qoff = ((size_t)bh*SS + s0 + g*16 + l15)*FF;
    bf16x8 qh[16], ql[16];
    #pragma unroll
    for (int ks = 0; ks < 16; ++ks) {
        qh[ks] = *(const bf16x8*)&Qhi[qoff + ks*32 + l16*8];
        ql[ks] = *(const bf16x8*)&Qlo[qoff + ks*32 + l16*8];
    }
    if (t < 64) { mrow[t] = -3.0e38f; lrow[t] = 0.0f; }

    const short* Kh = Khi + (size_t)bh*SS*FF;
    const short* Kl = Klo + (size_t)bh*SS*FF;
    const short* Vg = VtG + (size_t)bh*FF*SS;

    f32x4 o[16] = {};   // rows 16g..16g+15 x features [256h,256h+256)

    for (int kt = 0; kt < SS/32; ++kt) {
        const int k0 = kt*32;
        // ---- stage K hi/lo (512 threads, 4 chunks each/plane) ----
        #pragma unroll
        for (int i = 0; i < 4; ++i) {
            int idx = t + 512*i;
            int row = idx >> 6, c8 = (idx & 63)*8;
            *(bf16x8*)&Ksh[row][c8] = *(const bf16x8*)&Kh[(size_t)(k0+row)*FF + c8];
            *(bf16x8*)&Ksl[row][c8] = *(const bf16x8*)&Kl[(size_t)(k0+row)*FF + c8];
        }
        __syncthreads();                              // (1) K ready
        // ---- QK^T: 16 q-rows x 16 keys, split-bf16 (hh + hl + lh) ----
        f32x4 shh = {}, shl = {}, slh = {};
        #pragma unroll
        for (int ks = 0; ks < 16; ++ks) {
            bf16x8 bh8 = *(const bf16x8*)&Ksh[h*16 + l15][ks*32 + l16*8];
            bf16x8 bl8 = *(const bf16x8*)&Ksl[h*16 + l15][ks*32 + l16*8];
            shh = MFMA_B16(qh[ks], bh8, shh);
            shl = MFMA_B16(qh[ks], bl8, shl);
            slh = MFMA_B16(ql[ks], bh8, slh);
        }
        {
            f32x4 sv = shh + shl + slh;
            #pragma unroll
            for (int r = 0; r < 4; ++r)
                Ps[g*16 + l16*4 + r][h*16 + l15] = sv[r];
        }
        // ---- issue V^T loads early (hide HBM under softmax) ----
        bf16x8 vreg[4];
        #pragma unroll
        for (int i = 0; i < 4; ++i) {
            int idx = t + 512*i;
            int f = idx >> 2, c8 = (idx & 3)*8;
            vreg[i] = *(const bf16x8*)&Vg[(size_t)f*SS + k0 + c8];
        }
        __syncthreads();                              // (2) scores ready, K reads done
        #pragma unroll
        for (int i = 0; i < 4; ++i) {
            int idx = t + 512*i;
            int f = idx >> 2, c8 = (idx & 3)*8;
            *(bf16x8*)&Vts[f][c8] = vreg[i];
        }
        // ---- online softmax: 8 threads per row, 4 keys each ----
        {
            const int r = t >> 3, sub = t & 7;
            float sv[4];
            float mx = -3.0e38f;
            #pragma unroll
            for (int j = 0; j < 4; ++j) { sv[j] = Ps[r][sub*4 + j]; mx = fmaxf(mx, sv[j]); }
            mx = fmaxf(mx, __shfl_xor(mx, 1, 8));
            mx = fmaxf(mx, __shfl_xor(mx, 2, 8));
            mx = fmaxf(mx, __shfl_xor(mx, 4, 8));
            const float mold = mrow[r];
            const float mnew = fmaxf(mold, mx);
            float ls = 0.0f;
            #pragma unroll
            for (int j = 0; j < 4; ++j) {
                float p = __expf(sv[j] - mnew);
                ls += p;
                Pb[r][sub*4 + j] = f2bf(p);
            }
            ls += __shfl_xor(ls, 1, 8);
            ls += __shfl_xor(ls, 2, 8);
            ls += __shfl_xor(ls, 4, 8);
            if (sub == 0) {
                float sc = __expf(mold - mnew);
                srow[r] = sc;
                lrow[r] = lrow[r]*sc + ls;
                mrow[r] = mnew;
            }
        }
        __syncthreads();                              // (3) Pb, Vts, srow ready
        // ---- rescale + PV (plain bf16): 16 q-rows x 256 features ----
        #pragma unroll
        for (int r = 0; r < 4; ++r) {
            float sc = srow[g*16 + l16*4 + r];
            #pragma unroll
            for (int ff = 0; ff < 16; ++ff) o[ff][r] *= sc;
        }
        bf16x8 pa = *(const bf16x8*)&Pb[g*16 + l15][l16*8];
        #pragma unroll
        for (int ff = 0; ff < 16; ++ff) {
            bf16x8 vb = *(const bf16x8*)&Vts[h*256 + ff*16 + l15][l16*8];
            o[ff] = MFMA_B16(pa, vb, o[ff]);
        }
    }
    // ---- epilogue: Z = O/l + x (per-head residual), store hi/lo ----
    const int b = b_base + bh/HH;
    const float* xp = x + ((size_t)b*SS + s0)*FF;
    short* Zh = Zhi + ((size_t)bh*SS + s0)*FF;
    short* Zl = Zlo + ((size_t)bh*SS + s0)*FF;
    #pragma unroll
    for (int r = 0; r < 4; ++r) {
        const int q = g*16 + l16*4 + r;
        const float li = 1.0f / lrow[q];
        #pragma unroll
        for (int ff = 0; ff < 16; ++ff) {
            const int col = h*256 + ff*16 + l15;
            float zv = o[ff][r]*li + xp[(size_t)q*FF + col];
            short hh = f2bf(zv);
            Zh[(size_t)q*FF + col] = hh;
            Zl[(size_t)q*FF + col] = f2bf(zv - bf2f(hh));
        }
    }
}

// ============ Kernel 3: joiner GEMM, split-bf16 MFMA -> Jout fp32 ============
// grid (FF/128=4, cb*SS/64), block 256 (2x2 waves of 32x64)
__global__ __launch_bounds__(256,2)
void joiner_kernel(const short* __restrict__ Zhi, const short* __restrict__ Zlo,
                   const short* __restrict__ WjTh, const short* __restrict__ WjTl,
                   float* __restrict__ Jout)
{
    __shared__ short Ah[64][72], Al[64][72];
    __shared__ short Bh[128][72], Bl[128][72];
    const int t = threadIdx.x, lane = t & 63, w = t >> 6;
    const int l15 = lane & 15, l16 = lane >> 4;
    const int wm = (w >> 1)*32, wn = (w & 1)*64;
    const int n0 = blockIdx.x*128, m0 = blockIdx.y*64;
    const int bl = m0 >> 11;
    const int sl = m0 & (SS-1);
    f32x4 acc[2][4] = {};

    for (int k0 = 0; k0 < HH*FF; k0 += 64) {
        const int h = k0 >> 9, f0 = k0 & (FF-1);
        __syncthreads();
        #pragma unroll
        for (int i = 0; i < 2; ++i) {
            int idx = t + 256*i;
            int row = idx >> 3, c8 = (idx & 7)*8;
            size_t g = ((size_t)(bl*HH + h)*SS + sl + row)*FF + f0 + c8;
            *(bf16x8*)&Ah[row][c8] = *(const bf16x8*)&Zhi[g];
            *(bf16x8*)&Al[row][c8] = *(const bf16x8*)&Zlo[g];
        }
        #pragma unroll
        for (int i = 0; i < 4; ++i) {
            int idx = t + 256*i;
            int row = idx >> 3, c8 = (idx & 7)*8;
            size_t g = (size_t)(n0+row)*(HH*FF) + k0 + c8;
            *(bf16x8*)&Bh[row][c8] = *(const bf16x8*)&WjTh[g];
            *(bf16x8*)&Bl[row][c8] = *(const bf16x8*)&WjTl[g];
        }
        __syncthreads();
        #pragma unroll
        for (int ks = 0; ks < 2; ++ks) {
            bf16x8 a_h[2], a_l[2], b_h[4], b_l[4];
            #pragma unroll
            for (int mf = 0; mf < 2; ++mf) {
                a_h[mf] = *(const bf16x8*)&Ah[wm + mf*16 + l15][ks*32 + l16*8];
                a_l[mf] = *(const bf16x8*)&Al[wm + mf*16 + l15][ks*32 + l16*8];
            }
            #pragma unroll
            for (int nf = 0; nf < 4; ++nf) {
                b_h[nf] = *(const bf16x8*)&Bh[wn + nf*16 + l15][ks*32 + l16*8];
                b_l[nf] = *(const bf16x8*)&Bl[wn + nf*16 + l15][ks*32 + l16*8];
            }
            #pragma unroll
            for (int mf = 0; mf < 2; ++mf)
            #pragma unroll
            for (int nf = 0; nf < 4; ++nf) {
                acc[mf][nf] = MFMA_B16(a_h[mf], b_h[nf], acc[mf][nf]);
                acc[mf][nf] = MFMA_B16(a_h[mf], b_l[nf], acc[mf][nf]);
                acc[mf][nf] = MFMA_B16(a_l[mf], b_h[nf], acc[mf][nf]);
            }
        }
    }
    #pragma unroll
    for (int mf = 0; mf < 2; ++mf)
    #pragma unroll
    for (int nf = 0; nf < 4; ++nf)
    #pragma unroll
    for (int r = 0; r < 4; ++r)
        Jout[(size_t)(m0 + wm + mf*16 + l16*4 + r)*FF + n0 + wn + nf*16 + l15] = acc[mf][nf][r];
}

// ============ Kernel 4: residual + LayerNorm ============
// block 256 = 4 rows x 64 lanes; grid cb*SS/4
__global__ __launch_bounds__(256)
void ln_kernel(const float* __restrict__ x, const float* __restrict__ Jout,
               const float* __restrict__ gamma, const float* __restrict__ beta,
               float* __restrict__ out, int b_base)
{
    const int t = threadIdx.x, lane = t & 63;
    const int rl = blockIdx.x*4 + (t >> 6);
    const size_t gr = (size_t)b_base*SS + rl;
    const int c1 = lane*4, c2 = 256 + lane*4;
    float4 j1 = *(const float4*)&Jout[(size_t)rl*FF + c1];
    float4 j2 = *(const float4*)&Jout[(size_t)rl*FF + c2];
    float4 x1 = *(const float4*)&x[gr*FF + c1];
    float4 x2 = *(const float4*)&x[gr*FF + c2];
    float y[8];
    y[0]=j1.x+x1.x; y[1]=j1.y+x1.y; y[2]=j1.z+x1.z; y[3]=j1.w+x1.w;
    y[4]=j2.x+x2.x; y[5]=j2.y+x2.y; y[6]=j2.z+x2.z; y[7]=j2.w+x2.w;
    float s1 = 0.f, s2 = 0.f;
    #pragma unroll
    for (int j = 0; j < 8; ++j) { s1 += y[j]; s2 += y[j]*y[j]; }
    #pragma unroll
    for (int m = 1; m < 64; m <<= 1) {
        s1 += __shfl_xor(s1, m);
        s2 += __shfl_xor(s2, m);
    }
    const float mu = s1 * (1.0f/FF);
    float var = s2 * (1.0f/FF) - mu*mu;
    var = fmaxf(var, 0.0f);
    const float rs = rsqrtf(var + EPSV);
    float4 g1 = *(const float4*)&gamma[c1], g2 = *(const float4*)&gamma[c2];
    float4 b1 = *(const float4*)&beta[c1],  b2 = *(const float4*)&beta[c2];
    float4 o1, o2;
    o1.x = (y[0]-mu)*rs*g1.x + b1.x; o1.y = (y[1]-mu)*rs*g1.y + b1.y;
    o1.z = (y[2]-mu)*rs*g1.z + b1.z; o1.w = (y[3]-mu)*rs*g1.w + b1.w;
    o2.x = (y[4]-mu)*rs*g2.x + b2.x; o2.y = (y[5]-mu)*rs*g2.y + b2.y;
    o2.z = (y[6]-mu)*rs*g2.z + b2.z; o2.w = (y[7]-mu)*rs*g2.w + b2.w;
    *(float4*)&out[gr*FF + c1] = o1;
    *(float4*)&out[gr*FF + c2] = o2;
}

extern "C" void kernel_launch(void* const* d_in, const int* in_sizes, int n_in,
                              void* d_out, int out_size, void* d_ws, size_t ws_size,
                              hipStream_t stream)
{
    const float* x     = (const float*)d_in[0];
    const float* Wq    = (const float*)d_in[1];
    const float* Wk    = (const float*)d_in[2];
    const float* Wv    = (const float*)d_in[3];
    const float* Wj    = (const float*)d_in[4];
    const float* gamma = (const float*)d_in[5];
    const float* beta  = (const float*)d_in[6];
    float* out = (float*)d_out;

    // ---- workspace carve (bf16 planes as short) ----
    short* p = (short*)d_ws;
    short* xhi = p;  p += (size_t)BB*SS*FF;
    short* xlo = p;  p += (size_t)BB*SS*FF;
    short* Wth = p;  p += (size_t)3*HH*FF*FF;
    short* Wtl = p;  p += (size_t)3*HH*FF*FF;
    short* WjTh = p; p += (size_t)HH*FF*FF;
    short* WjTl = p; p += (size_t)HH*FF*FF;
    short* chunk0 = p;

    const size_t head_bytes = (size_t)(chunk0 - (short*)d_ws) * sizeof(short);
    const size_t plane_sh = (size_t)HH*SS*FF;                     // shorts/batch/plane
    const size_t per_batch_bytes = 7*plane_sh*sizeof(short) + (size_t)SS*FF*sizeof(float);
    int nb = 1;
    if (ws_size > head_bytes) {
        size_t m = (ws_size - head_bytes) / per_batch_bytes;
        nb = (m < 1) ? 1 : (m > BB ? BB : (int)m);
    }

    // ---- one-time preps ----
    prep_x_kernel<<<2048, 256, 0, stream>>>(x, xhi, xlo);
    prep_t_kernel<<<dim3(8,8,HH), 256, 0, stream>>>(Wq, Wth,                        Wtl,                        FF, FF);
    prep_t_kernel<<<dim3(8,8,HH), 256, 0, stream>>>(Wk, Wth + (size_t)HH*FF*FF,     Wtl + (size_t)HH*FF*FF,     FF, FF);
    prep_t_kernel<<<dim3(8,8,HH), 256, 0, stream>>>(Wv, Wth + (size_t)2*HH*FF*FF,   Wtl + (size_t)2*HH*FF*FF,   FF, FF);
    prep_t_kernel<<<dim3(8,64,1), 256, 0, stream>>>(Wj, WjTh, WjTl, HH*FF, FF);

    for (int b_base = 0; b_base < BB; b_base += nb) {
        int cb = (BB - b_base < nb) ? (BB - b_base) : nb;
        size_t pp = (size_t)cb*plane_sh;
        short* Qhi = chunk0;
        short* Qlo = Qhi + pp;
        short* Khi = Qlo + pp;
        short* Klo = Khi + pp;
        short* Vt  = Klo + pp;
        short* Zhi = Vt  + pp;
        short* Zlo = Zhi + pp;
        float* Jout = (float*)(Zlo + pp);
        const int nbh = cb*HH;

        proj_kernel<<<dim3(4,16,3*nbh), 256, 0, stream>>>(xhi, xlo, Wth, Wtl,
                                                          Qhi, Qlo, Khi, Klo, Vt, b_base, nbh);
        attn_kernel<<<dim3(SS/64, nbh), 512, 0, stream>>>(x, Qhi, Qlo, Khi, Klo, Vt,
                                                          Zhi, Zlo, b_base);
        joiner_kernel<<<dim3(4, cb*SS/64), 256, 0, stream>>>(Zhi, Zlo, WjTh, WjTl, Jout);
        ln_kernel<<<cb*SS/4, 256, 0, stream>>>(x, Jout, gamma, beta, out, b_base);
    }
}